// Round 11
// baseline (162.566 us; speedup 1.0000x reference)
//
#include <hip/hip_runtime.h>

#define H 256
#define W 256
#define OWID 250
#define BAND 10               // output rows per stream; 25*10 = 250
#define NBANDS 25
#define NW 3200               // waves; each wave = (imgA, imgA+128) x band
#define WPB 4                 // waves per block
#define NBLOCKS (NW / WPB)    // 800 blocks of 256 threads
#define RIN 16                // input rows per band
#define ROWB 1024             // bytes per image row (256 floats)

// Measured landmines (do not regress):
//  - R3/R4: ANY min-waves arg on __launch_bounds__ -> allocator spills
//    (WRITE_SIZE 0.2MB -> 85-114MB). Plain launch_bounds only.
//  - R6: re-rolling the row loop regressed. Keep full static unroll.
//  - R6/R8: L3-resident dispatches run the SAME time as HBM ones -> not BW-bound.
//  - R7: dual-stream ILP is the ONLY lever that cut per-wave row cost
//    (2.9K -> 1.8K cy), but VGPR 112 > 64 halved residency and canceled it.
//  - R9/R10: LDS ring and residency-matched grids are null; CU throughput is
//    ~6-8 rows/us/CU in every structure at VGPR<=64.
//  This round: R7's ILP-2 rebuilt inside the 64-VGPR tier — moments 32 +
//  enter depth-1 (16) + leave-at-use transients + SGPR-base addressing.

__device__ __forceinline__ float4 f4zero() { return make_float4(0.f, 0.f, 0.f, 0.f); }

// SSIM constants with 1/49 (=a) and 49/48 (=covn) folded in.
#define CC1 1e-4f             // (0.01)^2
#define CC2 9e-4f             // (0.03)^2
#define KAA (1.f / 2401.f)    // a^2
#define K2A (2.f / 2401.f)    // 2 a^2
#define KT1 (1.f / 24.f)      // 2 covn a
#define KT2 (-1.f / 1176.f)   // -2 covn a^2
#define KT3 (1.f / 48.f)      // covn a
#define KT4 (-1.f / 2352.f)   // -covn a^2

struct M4 { float4 sx, sy, sxy, spp; };   // vertical moments, one per stream

__device__ __forceinline__ float4 ld16(const char* b, int off) {
    return *(const float4*)(b + off);
}

// Vertical slide: + entering (xn,yn), - leaving (xo,yo).
__device__ __forceinline__ void slide(M4& m, const float4 xn, const float4 yn,
                                      const float4 xo, const float4 yo) {
    m.sx.x += xn.x - xo.x; m.sx.y += xn.y - xo.y;
    m.sx.z += xn.z - xo.z; m.sx.w += xn.w - xo.w;
    m.sy.x += yn.x - yo.x; m.sy.y += yn.y - yo.y;
    m.sy.z += yn.z - yo.z; m.sy.w += yn.w - yo.w;
    m.sxy.x = fmaf(xn.x, yn.x, fmaf(-xo.x, yo.x, m.sxy.x));
    m.sxy.y = fmaf(xn.y, yn.y, fmaf(-xo.y, yo.y, m.sxy.y));
    m.sxy.z = fmaf(xn.z, yn.z, fmaf(-xo.z, yo.z, m.sxy.z));
    m.sxy.w = fmaf(xn.w, yn.w, fmaf(-xo.w, yo.w, m.sxy.w));
    m.spp.x = fmaf(xn.x, xn.x, fmaf(yn.x, yn.x, fmaf(-xo.x, xo.x, fmaf(-yo.x, yo.x, m.spp.x))));
    m.spp.y = fmaf(xn.y, xn.y, fmaf(yn.y, yn.y, fmaf(-xo.y, xo.y, fmaf(-yo.y, yo.y, m.spp.y))));
    m.spp.z = fmaf(xn.z, xn.z, fmaf(yn.z, yn.z, fmaf(-xo.z, xo.z, fmaf(-yo.z, yo.z, m.spp.z))));
    m.spp.w = fmaf(xn.w, xn.w, fmaf(yn.w, yn.w, fmaf(-xo.w, xo.w, fmaf(-yo.w, yo.w, m.spp.w))));
}

// Horizontal 7-tap via prefix decomposition (R8-verified): 4 shuffles/moment.
__device__ __forceinline__ void hwin4(const float4 S, float w[4]) {
    const float p1 = S.x;
    const float p2 = p1 + S.y;
    const float p3 = p2 + S.z;
    const float E  = p3 + S.w;
    const float n3 = __shfl_down(p3, 1);
    const float nE = __shfl_down(E, 1);
    const float f1 = __shfl_down(p1, 2);
    const float f2 = __shfl_down(p2, 2);
    w[0] = E + n3;
    w[1] = (E - p1) + nE;
    w[2] = (E - p2) + nE + f1;
    w[3] = (E - p3) + nE + f2;
}

// One output row's windows + SSIM + masked accumulate (R8-verified).
__device__ __forceinline__ void outrow(const M4& m, const float m01,
                                       const float m23, float& lsum) {
    float wx[4], wy[4], wpp[4], wxy[4];
    hwin4(m.sx,  wx);
    hwin4(m.sy,  wy);
    hwin4(m.spp, wpp);
    hwin4(m.sxy, wxy);
    #pragma unroll
    for (int s = 0; s < 4; ++s) {
        const float P  = wx[s] * wy[s];
        const float Qs = fmaf(wy[s], wy[s], wx[s] * wx[s]);
        const float A1 = fmaf(K2A, P, CC1);
        const float B1 = fmaf(KAA, Qs, CC1);
        const float A2 = fmaf(KT1, wxy[s], fmaf(KT2, P, CC2));
        const float B2 = fmaf(KT3, wpp[s], fmaf(KT4, Qs, CC2));
        const float S  = (A1 * A2) * __builtin_amdgcn_rcpf(B1 * B2);
        lsum = fmaf(S, (s < 2) ? m01 : m23, lsum);  // branchless col mask
    }
}

template<int R>
__device__ __forceinline__ void step(
    const char* XA, const char* YA, const char* XB, const char* YB,
    const int lo, M4& a, M4& b,
    float4& exA, float4& eyA, float4& exB, float4& eyB,
    const float m01, const float m23, float& lsum)
{
    // ---- stream A: row R ----
    {
        const float4 xn = exA, yn = eyA;
        if constexpr (R + 1 < RIN) {                 // enter depth-1 refill
            exA = ld16(XA, lo + (R + 1) * ROWB);
            eyA = ld16(YA, lo + (R + 1) * ROWB);
        }
        float4 xo = f4zero(), yo = f4zero();
        if constexpr (R >= 7) {                      // leave at use (L2 hit);
            xo = ld16(XA, lo + (R - 7) * ROWB);      // latency covered by the
            yo = ld16(YA, lo + (R - 7) * ROWB);      // sibling stream's compute
        }
        slide(a, xn, yn, xo, yo);
        if constexpr (R >= 6) outrow(a, m01, m23, lsum);
    }
    // ---- stream B: row R (fully independent work) ----
    {
        const float4 xn = exB, yn = eyB;
        if constexpr (R + 1 < RIN) {
            exB = ld16(XB, lo + (R + 1) * ROWB);
            eyB = ld16(YB, lo + (R + 1) * ROWB);
        }
        float4 xo = f4zero(), yo = f4zero();
        if constexpr (R >= 7) {
            xo = ld16(XB, lo + (R - 7) * ROWB);
            yo = ld16(YB, lo + (R - 7) * ROWB);
        }
        slide(b, xn, yn, xo, yo);
        if constexpr (R >= 6) outrow(b, m01, m23, lsum);
    }
    if constexpr (R + 1 < RIN)
        step<R + 1>(XA, YA, XB, YB, lo, a, b, exA, eyA, exB, eyB, m01, m23, lsum);
}

__global__ __launch_bounds__(256) void ssim_band_kernel(
    const float* __restrict__ X, const float* __restrict__ Y,
    float* __restrict__ partial)
{
    const int lane = threadIdx.x & 63;          // owns cols 4*lane..4*lane+3
    const int wid  = blockIdx.x * WPB + (threadIdx.x >> 6);  // 0..3199
    const int imgA = wid / NBANDS;              // 0..127 (stream B: +128)
    const int band = wid % NBANDS;              // 0..24
    const int r0 = band * BAND;

    // Uniform (SGPR) base pointers; the ONLY per-lane address component is lo.
    const size_t baseA = ((size_t)imgA * H + r0) * ROWB;
    const size_t dB    = (size_t)128 * H * ROWB;
    const char* XA = (const char*)X + baseA;
    const char* YA = (const char*)Y + baseA;
    const char* XB = XA + dB;
    const char* YB = YA + dB;
    const int lo = lane * 16;

    M4 a, b;
    a.sx = f4zero(); a.sy = f4zero(); a.sxy = f4zero(); a.spp = f4zero();
    b.sx = f4zero(); b.sy = f4zero(); b.sxy = f4zero(); b.spp = f4zero();

    // Preload enter slots: row 0 of both streams.
    float4 exA = ld16(XA, lo), eyA = ld16(YA, lo);
    float4 exB = ld16(XB, lo), eyB = ld16(YB, lo);

    // Column-validity masks (output cols 0..249):
    //   cols 4L+{0,1} valid iff lane <= 62; cols 4L+{2,3} valid iff lane <= 61.
    const float m01 = (lane <= 62) ? 1.0f : 0.0f;
    const float m23 = (lane <= 61) ? 1.0f : 0.0f;

    float lsum = 0.0f;
    step<0>(XA, YA, XB, YB, lo, a, b, exA, eyA, exB, eyB, m01, m23, lsum);

    // Wave reduction -> one partial per wave (covers both streams).
    #pragma unroll
    for (int off = 32; off > 0; off >>= 1)
        lsum += __shfl_down(lsum, off, 64);
    if (lane == 0) partial[wid] = lsum;
}

__global__ __launch_bounds__(256) void ssim_reduce_kernel(
    const float* __restrict__ partial, float* __restrict__ out)
{
    const int tid = threadIdx.x;
    double acc = 0.0;
    for (int i = tid; i < NW; i += 256)
        acc += (double)partial[i];
    #pragma unroll
    for (int off = 32; off > 0; off >>= 1)
        acc += __shfl_down(acc, off, 64);
    __shared__ double wsumd[4];
    if ((tid & 63) == 0) wsumd[tid >> 6] = acc;
    __syncthreads();
    if (tid == 0) {
        double total = wsumd[0] + wsumd[1] + wsumd[2] + wsumd[3];
        float loss = (float)(1.0 - total / 16000000.0);
        out[0] = loss; out[1] = loss; out[2] = loss; out[3] = loss;
    }
}

extern "C" void kernel_launch(void* const* d_in, const int* in_sizes, int n_in,
                              void* d_out, int out_size, void* d_ws, size_t ws_size,
                              hipStream_t stream) {
    const float* X = (const float*)d_in[0];
    const float* Y = (const float*)d_in[1];
    // d_in[2] is the uniform 7x7 filter (1/49 everywhere) — constant-folded.
    float* out = (float*)d_out;
    float* partial = (float*)d_ws;   // 3200 floats = 12.8 KB

    hipLaunchKernelGGL(ssim_band_kernel, dim3(NBLOCKS), dim3(256), 0, stream,
                       X, Y, partial);
    hipLaunchKernelGGL(ssim_reduce_kernel, dim3(1), dim3(256), 0, stream,
                       partial, out);
}